// Round 4
// baseline (1037.611 us; speedup 1.0000x reference)
//
#include <hip/hip_runtime.h>

// LightGCN encoder on MI355X — round 11.
// Round 10 accounting: pulls 97 us, estimated bin+csr+init+final ~40 us, yet
// wall = 230 us -> ~90 us of per-dispatch overhead (~15 us x 6), consistent
// across rounds 7-10. This round cuts 6 dispatches to 3:
//   1. lgcn_bin        (unchanged; also zeroes the grid-barrier counter)
//   2. lgcn_build_csr  (+ fused g0 init: block b owns nodes [256b,256b+256),
//                       writes their bf16 g0 rows + zero rows; x4-unrolled
//                       strip-run gather for memory-level parallelism)
//   3. lgcn_prop       persistent kernel: pull1 -> grid barrier -> pull2 ->
//                       grid barrier -> final. 2048 blocks x 256 thr, 0 LDS,
//                       __launch_bounds__(256,8) => 8 blocks/CU, all 2048
//                       co-resident (barrier cannot deadlock). Device-scope
//                       release/acquire on the counter handles cross-XCD
//                       visibility (release flushes writer L2, acquire
//                       invalidates reader L1/L2).
#define N_USERS 100000
#define N_NODES 150000
#define DIM 64
#define BATCH 4096
#define BSHIFT 8
#define BUCKET 256
#define NB 586                 // ceil(150000 / 256) buckets
#define NBP 768                // padded bucket count for the 3-per-thread scan
#define PAIRS_PER_BLK 2048     // undirected pairs per binning block
#define STRIP 4096             // directed edges (words) per strip
#define CAPSHIFT 13
#define CAP (1 << CAPSHIFT)    // packed slots per bucket (max ~6.3K used)
#define PROP_BLOCKS 2048
#define PROP_WAVES (PROP_BLOCKS * 4)

typedef unsigned short bf16_t;

static __device__ __forceinline__ float bf2f(bf16_t h) {
    return __uint_as_float(((unsigned)h) << 16);
}
static __device__ __forceinline__ bf16_t f2bf(float f) {  // round-nearest-even
    unsigned u = __float_as_uint(f);
    return (bf16_t)((u + 0x7FFFu + ((u >> 16) & 1u)) >> 16);
}

// --- Strip sort: LDS counting-sort of 4096 directed edges by bucket --------
// binned word = (local_dst[8b]<<18)|src. pos[k*(NB+1)+b] = run start of
// bucket b in strip k; pos[k*(NB+1)+NB] = edge count of strip k.
__global__ void __launch_bounds__(256)
lgcn_bin(const int* __restrict__ row, const int* __restrict__ col,
         int* __restrict__ pos, int* __restrict__ binned, int EH,
         int* __restrict__ bar) {
    __shared__ int cnt[NBP];
    __shared__ int sA[256], sB[256];
    __shared__ int base[NB + 2];
    __shared__ int stage[STRIP];
    int tid = threadIdx.x;
    int k = blockIdx.x;
    if (k == 0 && tid == 0) bar[0] = 0;        // reset prop grid barrier
    cnt[tid] = 0; cnt[tid + 256] = 0; cnt[tid + 512] = 0;
    __syncthreads();
    int e0 = k * PAIRS_PER_BLK;
    int e1 = min(EH, e0 + PAIRS_PER_BLK);
    int n = e1 - e0;                           // pairs (multiple of 4)
    int nq = n >> 2;
    const int4* r4 = (const int4*)(row + e0);
    const int4* c4 = (const int4*)(col + e0);
    for (int q = tid; q < nq; q += 256) {
        int4 r = r4[q]; int4 c = c4[q];
        atomicAdd(&cnt[r.x >> BSHIFT], 1); atomicAdd(&cnt[c.x >> BSHIFT], 1);
        atomicAdd(&cnt[r.y >> BSHIFT], 1); atomicAdd(&cnt[c.y >> BSHIFT], 1);
        atomicAdd(&cnt[r.z >> BSHIFT], 1); atomicAdd(&cnt[c.z >> BSHIFT], 1);
        atomicAdd(&cnt[r.w >> BSHIFT], 1); atomicAdd(&cnt[c.w >> BSHIFT], 1);
    }
    __syncthreads();
    // Exclusive scan over NBP buckets, 3 per thread.
    int c0 = cnt[3 * tid], c1 = cnt[3 * tid + 1], c2 = cnt[3 * tid + 2];
    int s = c0 + c1 + c2;
    sA[tid] = s;
    __syncthreads();
    int* c_ = sA; int* n_ = sB;
    for (int off = 1; off < 256; off <<= 1) {
        n_[tid] = (tid >= off) ? c_[tid] + c_[tid - off] : c_[tid];
        __syncthreads();
        int* t = c_; c_ = n_; n_ = t;
    }
    int excl = c_[tid] - s;
    if (3 * tid     <= NB) base[3 * tid]     = excl;
    if (3 * tid + 1 <= NB) base[3 * tid + 1] = excl + c0;
    if (3 * tid + 2 <= NB) base[3 * tid + 2] = excl + c0 + c1;
    __syncthreads();
    // pos table (coalesced) + LDS cursors (reuse cnt).
    for (int i = tid; i <= NB; i += 256) {
        pos[k * (NB + 1) + i] = base[i];
        cnt[i] = base[i];
    }
    __syncthreads();
    // LDS scatter (re-read pairs; L2-hot).
    for (int q = tid; q < nq; q += 256) {
        int4 r = r4[q]; int4 c = c4[q];
        int rr[4] = { r.x, r.y, r.z, r.w };
        int cc[4] = { c.x, c.y, c.z, c.w };
#pragma unroll
        for (int j = 0; j < 4; ++j) {
            int p1 = atomicAdd(&cnt[cc[j] >> BSHIFT], 1);
            stage[p1] = ((cc[j] & (BUCKET - 1)) << 18) | rr[j];
            int p2 = atomicAdd(&cnt[rr[j] >> BSHIFT], 1);
            stage[p2] = ((rr[j] & (BUCKET - 1)) << 18) | cc[j];
        }
    }
    __syncthreads();
    // Coalesced strip write-out.
    int m4 = (2 * n) >> 2;
    int4* dst = (int4*)(binned + k * STRIP);
    const int4* st4 = (const int4*)stage;
    for (int j = tid; j < m4; j += 256) dst[j] = st4[j];
}

// --- Per-bucket padded CSR + fused g0 init ---------------------------------
// Node segments padded to multiple of 4; pad slots = N_NODES (zero row).
// nodeinfo = {start, deg, bits(1/sqrt(da)), bits(sqrt(da))}.
// Also writes g0 = norm*x (bf16) for this bucket's nodes + zero rows (blk 0).
__global__ void __launch_bounds__(256)
lgcn_build_csr(const int* __restrict__ pos, const int* __restrict__ binned,
               int4* __restrict__ nodeinfo, int* __restrict__ packed,
               const float* __restrict__ ue, const float* __restrict__ ie,
               bf16_t* __restrict__ g0, bf16_t* __restrict__ g1, int nblk) {
    __shared__ int stage[CAP];     // gathered edges of this bucket
    __shared__ int sorted[CAP];    // node-sorted + padded
    __shared__ int sA[256], sB[256];
    __shared__ int hist[256], cur[256];
    int b = blockIdx.x;
    int tid = threadIdx.x;
    // Runs for strips tid and tid+256.
    int a0 = 0, l0 = 0, a1 = 0, l1 = 0;
    if (tid < nblk) {
        const int* pk = pos + tid * (NB + 1) + b;
        a0 = pk[0]; l0 = pk[1] - a0;
    }
    if (tid + 256 < nblk) {
        const int* pk = pos + (tid + 256) * (NB + 1) + b;
        a1 = pk[0]; l1 = pk[1] - a1;
    }
    int u = l0 + l1;
    sA[tid] = u;
    __syncthreads();
    int* c_ = sA; int* n_ = sB;
    for (int off = 1; off < 256; off <<= 1) {
        n_[tid] = (tid >= off) ? c_[tid] + c_[tid - off] : c_[tid];
        __syncthreads();
        int* t = c_; c_ = n_; n_ = t;
    }
    int myBase = c_[tid] - u;
    int Eb = c_[255];
    __syncthreads();
    // Gather runs into stage (short scattered reads, x4 unrolled for MLP).
    {
        const int* s0 = binned + tid * STRIP + a0;
        int i = 0;
        for (; i + 4 <= l0; i += 4) {
            int w0 = s0[i], w1 = s0[i + 1], w2 = s0[i + 2], w3 = s0[i + 3];
            stage[myBase + i] = w0;     stage[myBase + i + 1] = w1;
            stage[myBase + i + 2] = w2; stage[myBase + i + 3] = w3;
        }
        for (; i < l0; ++i) stage[myBase + i] = s0[i];
        const int* s1 = binned + (tid + 256) * STRIP + a1;
        int bb = myBase + l0;
        i = 0;
        for (; i + 4 <= l1; i += 4) {
            int w0 = s1[i], w1 = s1[i + 1], w2 = s1[i + 2], w3 = s1[i + 3];
            stage[bb + i] = w0;     stage[bb + i + 1] = w1;
            stage[bb + i + 2] = w2; stage[bb + i + 3] = w3;
        }
        for (; i < l1; ++i) stage[bb + i] = s1[i];
    }
    hist[tid] = 0;
    __syncthreads();
    for (int j = tid; j < Eb; j += 256)
        atomicAdd(&hist[stage[j] >> 18], 1);
    __syncthreads();
    int deg = hist[tid];
    int degp = (deg + 3) & ~3;               // padded segment length
    sA[tid] = degp;
    __syncthreads();
    int* c2 = sA; int* n2 = sB;
    for (int off = 1; off < 256; off <<= 1) {
        n2[tid] = (tid >= off) ? c2[tid] + c2[tid - off] : c2[tid];
        __syncthreads();
        int* t = c2; c2 = n2; n2 = t;
    }
    int startLoc = c2[tid] - degp;           // local, int4-aligned
    int totPad = c2[255];
    cur[tid] = startLoc;
    int gstart = (b << CAPSHIFT) + startLoc;
    int node = (b << BSHIFT) + tid;
    float da = (deg == 0) ? 1.0f : (float)deg;
    float sq = sqrtf(da);
    float nm = 1.0f / sq;
    if (node < N_NODES) {
        int4 ni;
        ni.x = gstart;
        ni.y = deg;
        ni.z = __float_as_int(nm);
        ni.w = __float_as_int(sq);
        nodeinfo[node] = ni;
    }
    __syncthreads();                          // all hist reads done
    hist[tid] = __float_as_int(nm);           // reuse hist as norm table
    // Prefill (covers pad slots with the zero row).
    for (int j = tid; j < totPad; j += 256) sorted[j] = N_NODES;
    __syncthreads();
    for (int j = tid; j < Eb; j += 256) {
        int w = stage[j];
        int p = atomicAdd(&cur[w >> 18], 1);  // LDS atomic
        sorted[p] = w & 0x3FFFF;
    }
    __syncthreads();
    // Coalesced bucket-region write-out.
    int4* dst = (int4*)(packed + (b << CAPSHIFT));
    const int4* s4 = (const int4*)sorted;
    for (int j = tid; j < (totPad >> 2); j += 256) dst[j] = s4[j];
    // --- Fused g0 init for this bucket's nodes (flat chunk range is
    // contiguous: t = b*4096 + i, i in [0, nloc*16)). -----------------------
    int firstNode = b << BSHIFT;
    int nloc = min(BUCKET, N_NODES - firstNode);
    const int nU16 = N_USERS * (DIM / 4);
    int t0 = firstNode * (DIM / 4);
    for (int i = tid; i < nloc * (DIM / 4); i += 256) {
        int t = t0 + i;
        float4 x = (t < nU16) ? ((const float4*)ue)[t]
                              : ((const float4*)ie)[t - nU16];
        float nrm = __int_as_float(hist[i >> 4]);
        ushort4 o;
        o.x = f2bf(x.x * nrm); o.y = f2bf(x.y * nrm);
        o.z = f2bf(x.z * nrm); o.w = f2bf(x.w * nrm);
        ((ushort4*)g0)[t] = o;
    }
    if (b == 0 && tid < 32) {                 // zero rows in both buffers
        const int nT = N_NODES * (DIM / 4);
        if (tid < 16) ((ushort4*)g0)[nT + tid] = make_ushort4(0, 0, 0, 0);
        else          ((ushort4*)g1)[nT + tid - 16] = make_ushort4(0, 0, 0, 0);
    }
}

// --- Propagation (persistent) ----------------------------------------------

// Gather core: 16-lane group sums g rows for edges [start, start+deg).
static __device__ __forceinline__ float4
gather_sum(const bf16_t* g, const int* packed, int start, int deg,
           int grp, int c) {
    float4 acc = make_float4(0.f, 0.f, 0.f, 0.f);
    for (int o = 4 * grp; o < deg; o += 16) {
        int4 e4 = *(const int4*)(packed + start + o);  // 16-B aligned
        ushort4 v0 = ((const ushort4*)(g + (size_t)e4.x * DIM))[c];
        ushort4 v1 = ((const ushort4*)(g + (size_t)e4.y * DIM))[c];
        ushort4 v2 = ((const ushort4*)(g + (size_t)e4.z * DIM))[c];
        ushort4 v3 = ((const ushort4*)(g + (size_t)e4.w * DIM))[c];
        acc.x += bf2f(v0.x); acc.y += bf2f(v0.y);
        acc.z += bf2f(v0.z); acc.w += bf2f(v0.w);
        acc.x += bf2f(v1.x); acc.y += bf2f(v1.y);
        acc.z += bf2f(v1.z); acc.w += bf2f(v1.w);
        acc.x += bf2f(v2.x); acc.y += bf2f(v2.y);
        acc.z += bf2f(v2.z); acc.w += bf2f(v2.w);
        acc.x += bf2f(v3.x); acc.y += bf2f(v3.y);
        acc.z += bf2f(v3.z); acc.w += bf2f(v3.w);
    }
    return acc;
}

static __device__ __forceinline__ void
wave_reduce(float4& acc) {
#pragma unroll
    for (int off = 16; off < 64; off <<= 1) {
        acc.x += __shfl_xor(acc.x, off, 64);
        acc.y += __shfl_xor(acc.y, off, 64);
        acc.z += __shfl_xor(acc.z, off, 64);
        acc.w += __shfl_xor(acc.w, off, 64);
    }
}

// Device-scope grid barrier (monotonic counter; caller supplies target).
static __device__ __forceinline__ void
grid_barrier(int* bar, int target) {
    __syncthreads();
    if (threadIdx.x == 0) {
        __threadfence();                      // release prior writes
        __hip_atomic_fetch_add(bar, 1, __ATOMIC_RELEASE, __HIP_MEMORY_SCOPE_AGENT);
        while (__hip_atomic_load(bar, __ATOMIC_ACQUIRE, __HIP_MEMORY_SCOPE_AGENT)
               < target)
            __builtin_amdgcn_s_sleep(2);
    }
    __syncthreads();
}

// Persistent: pull1 (gB = P(gA)) | barrier | pull2 (gA = P(gB)) | barrier |
// final (batch epilogue reading gB=g1, gA=g2).
__global__ void __launch_bounds__(256, 8)
lgcn_prop(bf16_t* gA, bf16_t* gB, const int4* nodeinfo, const int* packed,
          const float* ue, const float* ie, const int* uid, const int* iid,
          float* out, int* bar) {
    int gw = blockIdx.x * 4 + (threadIdx.x >> 6);      // global wave id
    int lane = threadIdx.x & 63;
    int grp = lane >> 4;
    int c = lane & 15;
    // pull 1
    for (int n = gw; n < N_NODES; n += PROP_WAVES) {
        int4 ni = nodeinfo[n];
        float4 acc = gather_sum(gA, packed, ni.x, ni.y, grp, c);
        wave_reduce(acc);
        if (lane < 16) {
            float nm = __int_as_float(ni.z);
            float s2 = nm * nm;
            ushort4 o;
            o.x = f2bf(acc.x * s2); o.y = f2bf(acc.y * s2);
            o.z = f2bf(acc.z * s2); o.w = f2bf(acc.w * s2);
            ((ushort4*)(gB + (size_t)n * DIM))[c] = o;
        }
    }
    grid_barrier(bar, PROP_BLOCKS);
    // pull 2
    for (int n = gw; n < N_NODES; n += PROP_WAVES) {
        int4 ni = nodeinfo[n];
        float4 acc = gather_sum(gB, packed, ni.x, ni.y, grp, c);
        wave_reduce(acc);
        if (lane < 16) {
            float nm = __int_as_float(ni.z);
            float s2 = nm * nm;
            ushort4 o;
            o.x = f2bf(acc.x * s2); o.y = f2bf(acc.y * s2);
            o.z = f2bf(acc.z * s2); o.w = f2bf(acc.w * s2);
            ((ushort4*)(gA + (size_t)n * DIM))[c] = o;
        }
    }
    grid_barrier(bar, 2 * PROP_BLOCKS);
    // final: one slot per wave (8192 waves = 2*BATCH slots)
    int slot = gw;
    if (slot < 2 * BATCH) {
        int isItem = slot >= BATCH;
        int b = isItem ? (slot - BATCH) : slot;
        int node = isItem ? (N_USERS + iid[b]) : uid[b];
        int4 ni = nodeinfo[node];
        float4 acc = gather_sum(gA, packed, ni.x, ni.y, grp, c);
        wave_reduce(acc);
        if (lane < 16) {
            const float* xb = isItem ? (ie + (size_t)(node - N_USERS) * DIM)
                                     : (ue + (size_t)node * DIM);
            float4 x = ((const float4*)xb)[c];
            ushort4 a1 = ((const ushort4*)(gB + (size_t)node * DIM))[c];
            ushort4 a2 = ((const ushort4*)(gA + (size_t)node * DIM))[c];
            float rn = __int_as_float(ni.w);
            float nm = __int_as_float(ni.z);
            float4 r;
            r.x = 0.25f * (x.x + rn * (bf2f(a1.x) + bf2f(a2.x)) + nm * acc.x);
            r.y = 0.25f * (x.y + rn * (bf2f(a1.y) + bf2f(a2.y)) + nm * acc.y);
            r.z = 0.25f * (x.z + rn * (bf2f(a1.z) + bf2f(a2.z)) + nm * acc.z);
            r.w = 0.25f * (x.w + rn * (bf2f(a1.w) + bf2f(a2.w)) + nm * acc.w);
            ((float4*)(out + (size_t)slot * DIM))[c] = r;
        }
    }
}

// --- Launch ----------------------------------------------------------------

extern "C" void kernel_launch(void* const* d_in, const int* in_sizes, int n_in,
                              void* d_out, int out_size, void* d_ws, size_t ws_size,
                              hipStream_t stream) {
    const float* ue  = (const float*)d_in[0];
    const float* ie  = (const float*)d_in[1];
    const int*   ei  = (const int*)d_in[3];
    const int*   uid = (const int*)d_in[4];
    const int*   iid = (const int*)d_in[5];
    float* out = (float*)d_out;

    const int E  = in_sizes[2];     // 2,000,000 directed edges
    const int EH = E / 2;           // 1,000,000 undirected pairs
    const int* row = ei;            // first-half src = user ids
    const int* col = ei + E;        // first-half dst = item node ids

    const int nblk = (EH + PAIRS_PER_BLK - 1) / PAIRS_PER_BLK;   // 489

    // Workspace carve-up (256-B aligned), ~58 MB total.
    char* p = (char*)d_ws;
    size_t off = 0;
    auto carve = [&](size_t bytes) -> char* {
        char* r = p + off;
        off += (bytes + 255) & ~(size_t)255;
        return r;
    };
    const size_t nodeBf16 = (size_t)(N_NODES + 1) * DIM * sizeof(bf16_t); // +zero row
    bf16_t* gA       = (bf16_t*)carve(nodeBf16);
    bf16_t* gB       = (bf16_t*)carve(nodeBf16);
    int4*   nodeinfo = (int4*)carve((size_t)N_NODES * sizeof(int4));       // 2.4 MB
    int*    pos      = (int*)carve((size_t)nblk * (NB + 1) * sizeof(int)); // 1.15 MB
    int*    binned   = (int*)carve((size_t)nblk * STRIP * sizeof(int));    // 8 MB
    int*    packed   = (int*)carve((size_t)NB * CAP * sizeof(int));        // 19.2 MB
    int*    bar      = (int*)carve(256);
    (void)ws_size;

    // 1) Strip sort (also resets the grid barrier).
    lgcn_bin<<<nblk, 256, 0, stream>>>(row, col, pos, binned, EH, bar);
    // 2) Per-bucket CSR + fused g0 init + zero rows.
    lgcn_build_csr<<<NB, 256, 0, stream>>>(pos, binned, nodeinfo, packed,
                                           ue, ie, gA, gB, nblk);
    // 3) Persistent propagation: pull, pull, final with grid barriers.
    lgcn_prop<<<PROP_BLOCKS, 256, 0, stream>>>(gA, gB, nodeinfo, packed,
                                               ue, ie, uid, iid, out, bar);
}

// Round 5
// 229.804 us; speedup vs baseline: 4.5152x; 4.5152x over previous
//
#include <hip/hip_runtime.h>

// LightGCN encoder on MI355X — round 12.
// Round 11 post-mortem: the persistent kernel's spin barrier (2048 blocks,
// RELEASE RMW + ACQUIRE polls on one line) stalled the whole chip 10x
// (FETCH unchanged => no cache nuking; pure coherence-op serialization).
// But it measured the pieces: bin+csr+init ~ 55-60 us, dispatch gap ~ 13 us.
// Round 12 reverts to the proven multi-dispatch structure and keeps round
// 11's verified csr+g0-init fusion: 6 dispatches -> 5.
//   1. lgcn_bin        strip counting-sort (proven, r10)
//   2. lgcn_build_csr  per-bucket CSR + fused g0 init (proven, r11)
//   3. lgcn_pull       g1 = P(g0)   (proven, r10)
//   4. lgcn_pull       g2 = P(g1)
//   5. lgcn_final      batch epilogue (proven, r10)
#define N_USERS 100000
#define N_NODES 150000
#define DIM 64
#define BATCH 4096
#define BSHIFT 8
#define BUCKET 256
#define NB 586                 // ceil(150000 / 256) buckets
#define NBP 768                // padded bucket count for the 3-per-thread scan
#define PAIRS_PER_BLK 2048     // undirected pairs per binning block
#define STRIP 4096             // directed edges (words) per strip
#define CAPSHIFT 13
#define CAP (1 << CAPSHIFT)    // packed slots per bucket (max ~6.3K used)

typedef unsigned short bf16_t;

static __device__ __forceinline__ float bf2f(bf16_t h) {
    return __uint_as_float(((unsigned)h) << 16);
}
static __device__ __forceinline__ bf16_t f2bf(float f) {  // round-nearest-even
    unsigned u = __float_as_uint(f);
    return (bf16_t)((u + 0x7FFFu + ((u >> 16) & 1u)) >> 16);
}

// --- Strip sort: LDS counting-sort of 4096 directed edges by bucket --------
// binned word = (local_dst[8b]<<18)|src. pos[k*(NB+1)+b] = run start of
// bucket b in strip k; pos[k*(NB+1)+NB] = edge count of strip k.
__global__ void __launch_bounds__(256)
lgcn_bin(const int* __restrict__ row, const int* __restrict__ col,
         int* __restrict__ pos, int* __restrict__ binned, int EH) {
    __shared__ int cnt[NBP];
    __shared__ int sA[256], sB[256];
    __shared__ int base[NB + 2];
    __shared__ int stage[STRIP];
    int tid = threadIdx.x;
    int k = blockIdx.x;
    cnt[tid] = 0; cnt[tid + 256] = 0; cnt[tid + 512] = 0;
    __syncthreads();
    int e0 = k * PAIRS_PER_BLK;
    int e1 = min(EH, e0 + PAIRS_PER_BLK);
    int n = e1 - e0;                           // pairs (multiple of 4)
    int nq = n >> 2;
    const int4* r4 = (const int4*)(row + e0);
    const int4* c4 = (const int4*)(col + e0);
    for (int q = tid; q < nq; q += 256) {
        int4 r = r4[q]; int4 c = c4[q];
        atomicAdd(&cnt[r.x >> BSHIFT], 1); atomicAdd(&cnt[c.x >> BSHIFT], 1);
        atomicAdd(&cnt[r.y >> BSHIFT], 1); atomicAdd(&cnt[c.y >> BSHIFT], 1);
        atomicAdd(&cnt[r.z >> BSHIFT], 1); atomicAdd(&cnt[c.z >> BSHIFT], 1);
        atomicAdd(&cnt[r.w >> BSHIFT], 1); atomicAdd(&cnt[c.w >> BSHIFT], 1);
    }
    __syncthreads();
    // Exclusive scan over NBP buckets, 3 per thread.
    int c0 = cnt[3 * tid], c1 = cnt[3 * tid + 1], c2 = cnt[3 * tid + 2];
    int s = c0 + c1 + c2;
    sA[tid] = s;
    __syncthreads();
    int* c_ = sA; int* n_ = sB;
    for (int off = 1; off < 256; off <<= 1) {
        n_[tid] = (tid >= off) ? c_[tid] + c_[tid - off] : c_[tid];
        __syncthreads();
        int* t = c_; c_ = n_; n_ = t;
    }
    int excl = c_[tid] - s;
    if (3 * tid     <= NB) base[3 * tid]     = excl;
    if (3 * tid + 1 <= NB) base[3 * tid + 1] = excl + c0;
    if (3 * tid + 2 <= NB) base[3 * tid + 2] = excl + c0 + c1;
    __syncthreads();
    // pos table (coalesced) + LDS cursors (reuse cnt).
    for (int i = tid; i <= NB; i += 256) {
        pos[k * (NB + 1) + i] = base[i];
        cnt[i] = base[i];
    }
    __syncthreads();
    // LDS scatter (re-read pairs; L2-hot).
    for (int q = tid; q < nq; q += 256) {
        int4 r = r4[q]; int4 c = c4[q];
        int rr[4] = { r.x, r.y, r.z, r.w };
        int cc[4] = { c.x, c.y, c.z, c.w };
#pragma unroll
        for (int j = 0; j < 4; ++j) {
            int p1 = atomicAdd(&cnt[cc[j] >> BSHIFT], 1);
            stage[p1] = ((cc[j] & (BUCKET - 1)) << 18) | rr[j];
            int p2 = atomicAdd(&cnt[rr[j] >> BSHIFT], 1);
            stage[p2] = ((rr[j] & (BUCKET - 1)) << 18) | cc[j];
        }
    }
    __syncthreads();
    // Coalesced strip write-out.
    int m4 = (2 * n) >> 2;
    int4* dst = (int4*)(binned + k * STRIP);
    const int4* st4 = (const int4*)stage;
    for (int j = tid; j < m4; j += 256) dst[j] = st4[j];
}

// --- Per-bucket padded CSR + fused g0 init ---------------------------------
// Node segments padded to multiple of 4; pad slots = N_NODES (zero row).
// nodeinfo = {start, deg, bits(1/sqrt(da)), bits(sqrt(da))}.
// Also writes g0 = norm*x (bf16) for this bucket's nodes + zero rows (blk 0).
__global__ void __launch_bounds__(256)
lgcn_build_csr(const int* __restrict__ pos, const int* __restrict__ binned,
               int4* __restrict__ nodeinfo, int* __restrict__ packed,
               const float* __restrict__ ue, const float* __restrict__ ie,
               bf16_t* __restrict__ g0, bf16_t* __restrict__ g1, int nblk) {
    __shared__ int stage[CAP];     // gathered edges of this bucket
    __shared__ int sorted[CAP];    // node-sorted + padded
    __shared__ int sA[256], sB[256];
    __shared__ int hist[256], cur[256];
    int b = blockIdx.x;
    int tid = threadIdx.x;
    // Runs for strips tid and tid+256.
    int a0 = 0, l0 = 0, a1 = 0, l1 = 0;
    if (tid < nblk) {
        const int* pk = pos + tid * (NB + 1) + b;
        a0 = pk[0]; l0 = pk[1] - a0;
    }
    if (tid + 256 < nblk) {
        const int* pk = pos + (tid + 256) * (NB + 1) + b;
        a1 = pk[0]; l1 = pk[1] - a1;
    }
    int u = l0 + l1;
    sA[tid] = u;
    __syncthreads();
    int* c_ = sA; int* n_ = sB;
    for (int off = 1; off < 256; off <<= 1) {
        n_[tid] = (tid >= off) ? c_[tid] + c_[tid - off] : c_[tid];
        __syncthreads();
        int* t = c_; c_ = n_; n_ = t;
    }
    int myBase = c_[tid] - u;
    int Eb = c_[255];
    __syncthreads();
    // Gather runs into stage (short scattered reads, x4 unrolled for MLP).
    {
        const int* s0 = binned + tid * STRIP + a0;
        int i = 0;
        for (; i + 4 <= l0; i += 4) {
            int w0 = s0[i], w1 = s0[i + 1], w2 = s0[i + 2], w3 = s0[i + 3];
            stage[myBase + i] = w0;     stage[myBase + i + 1] = w1;
            stage[myBase + i + 2] = w2; stage[myBase + i + 3] = w3;
        }
        for (; i < l0; ++i) stage[myBase + i] = s0[i];
        const int* s1 = binned + (tid + 256) * STRIP + a1;
        int bb = myBase + l0;
        i = 0;
        for (; i + 4 <= l1; i += 4) {
            int w0 = s1[i], w1 = s1[i + 1], w2 = s1[i + 2], w3 = s1[i + 3];
            stage[bb + i] = w0;     stage[bb + i + 1] = w1;
            stage[bb + i + 2] = w2; stage[bb + i + 3] = w3;
        }
        for (; i < l1; ++i) stage[bb + i] = s1[i];
    }
    hist[tid] = 0;
    __syncthreads();
    for (int j = tid; j < Eb; j += 256)
        atomicAdd(&hist[stage[j] >> 18], 1);
    __syncthreads();
    int deg = hist[tid];
    int degp = (deg + 3) & ~3;               // padded segment length
    sA[tid] = degp;
    __syncthreads();
    int* c2 = sA; int* n2 = sB;
    for (int off = 1; off < 256; off <<= 1) {
        n2[tid] = (tid >= off) ? c2[tid] + c2[tid - off] : c2[tid];
        __syncthreads();
        int* t = c2; c2 = n2; n2 = t;
    }
    int startLoc = c2[tid] - degp;           // local, int4-aligned
    int totPad = c2[255];
    cur[tid] = startLoc;
    int gstart = (b << CAPSHIFT) + startLoc;
    int node = (b << BSHIFT) + tid;
    float da = (deg == 0) ? 1.0f : (float)deg;
    float sq = sqrtf(da);
    float nm = 1.0f / sq;
    if (node < N_NODES) {
        int4 ni;
        ni.x = gstart;
        ni.y = deg;
        ni.z = __float_as_int(nm);
        ni.w = __float_as_int(sq);
        nodeinfo[node] = ni;
    }
    __syncthreads();                          // all hist reads done
    hist[tid] = __float_as_int(nm);           // reuse hist as norm table
    // Prefill (covers pad slots with the zero row).
    for (int j = tid; j < totPad; j += 256) sorted[j] = N_NODES;
    __syncthreads();
    for (int j = tid; j < Eb; j += 256) {
        int w = stage[j];
        int p = atomicAdd(&cur[w >> 18], 1);  // LDS atomic
        sorted[p] = w & 0x3FFFF;
    }
    __syncthreads();
    // Coalesced bucket-region write-out.
    int4* dst = (int4*)(packed + (b << CAPSHIFT));
    const int4* s4 = (const int4*)sorted;
    for (int j = tid; j < (totPad >> 2); j += 256) dst[j] = s4[j];
    // --- Fused g0 init for this bucket's nodes (flat chunk range is
    // contiguous: t = b*4096 + i, i in [0, nloc*16)). -----------------------
    int firstNode = b << BSHIFT;
    int nloc = min(BUCKET, N_NODES - firstNode);
    const int nU16 = N_USERS * (DIM / 4);
    int t0 = firstNode * (DIM / 4);
    for (int i = tid; i < nloc * (DIM / 4); i += 256) {
        int t = t0 + i;
        float4 x = (t < nU16) ? ((const float4*)ue)[t]
                              : ((const float4*)ie)[t - nU16];
        float nrm = __int_as_float(hist[i >> 4]);
        ushort4 o;
        o.x = f2bf(x.x * nrm); o.y = f2bf(x.y * nrm);
        o.z = f2bf(x.z * nrm); o.w = f2bf(x.w * nrm);
        ((ushort4*)g0)[t] = o;
    }
    if (b == 0 && tid < 32) {                 // zero rows in both buffers
        const int nT = N_NODES * (DIM / 4);
        if (tid < 16) ((ushort4*)g0)[nT + tid] = make_ushort4(0, 0, 0, 0);
        else          ((ushort4*)g1)[nT + tid - 16] = make_ushort4(0, 0, 0, 0);
    }
}

// --- Propagation -----------------------------------------------------------

// Gather core: 16-lane group sums g rows for edges [start, start+deg).
// Pad slots point at the zero row -> plain adds, no clamps, no weights.
static __device__ __forceinline__ float4
gather_sum(const bf16_t* __restrict__ g, const int* __restrict__ packed,
           int start, int deg, int grp, int c) {
    float4 acc = make_float4(0.f, 0.f, 0.f, 0.f);
    for (int o = 4 * grp; o < deg; o += 16) {
        int4 e4 = *(const int4*)(packed + start + o);  // 16-B aligned
        ushort4 v0 = ((const ushort4*)(g + (size_t)e4.x * DIM))[c];
        ushort4 v1 = ((const ushort4*)(g + (size_t)e4.y * DIM))[c];
        ushort4 v2 = ((const ushort4*)(g + (size_t)e4.z * DIM))[c];
        ushort4 v3 = ((const ushort4*)(g + (size_t)e4.w * DIM))[c];
        acc.x += bf2f(v0.x); acc.y += bf2f(v0.y);
        acc.z += bf2f(v0.z); acc.w += bf2f(v0.w);
        acc.x += bf2f(v1.x); acc.y += bf2f(v1.y);
        acc.z += bf2f(v1.z); acc.w += bf2f(v1.w);
        acc.x += bf2f(v2.x); acc.y += bf2f(v2.y);
        acc.z += bf2f(v2.z); acc.w += bf2f(v2.w);
        acc.x += bf2f(v3.x); acc.y += bf2f(v3.y);
        acc.z += bf2f(v3.z); acc.w += bf2f(v3.w);
    }
    return acc;
}

// Full pull: gn[n] = bf16( norm[n]^2 * sum_{s in N(n)} g[s] ).
__global__ void __launch_bounds__(256)
lgcn_pull(const bf16_t* __restrict__ g, const int4* __restrict__ nodeinfo,
          const int* __restrict__ packed, bf16_t* __restrict__ gn) {
    int n = blockIdx.x * 4 + (threadIdx.x >> 6);
    if (n >= N_NODES) return;
    int lane = threadIdx.x & 63;
    int grp = lane >> 4;
    int c = lane & 15;
    int4 ni = nodeinfo[n];
    float4 acc = gather_sum(g, packed, ni.x, ni.y, grp, c);
#pragma unroll
    for (int off = 16; off < 64; off <<= 1) {
        acc.x += __shfl_xor(acc.x, off, 64);
        acc.y += __shfl_xor(acc.y, off, 64);
        acc.z += __shfl_xor(acc.z, off, 64);
        acc.w += __shfl_xor(acc.w, off, 64);
    }
    if (lane < 16) {
        float nm = __int_as_float(ni.z);
        float s2 = nm * nm;
        ushort4 o;
        o.x = f2bf(acc.x * s2); o.y = f2bf(acc.y * s2);
        o.z = f2bf(acc.z * s2); o.w = f2bf(acc.w * s2);
        ((ushort4*)(gn + (size_t)n * DIM))[c] = o;
    }
}

// Fused layer-3 + epilogue, batch nodes only:
// out[slot] = 0.25*( x[n] + rn*g1[n] + rn*g2[n] + nm*sum_{s in N(n)} g2[s] ).
__global__ void __launch_bounds__(256)
lgcn_final(const float* __restrict__ ue, const float* __restrict__ ie,
           const bf16_t* __restrict__ g1, const bf16_t* __restrict__ g2,
           const int4* __restrict__ nodeinfo, const int* __restrict__ packed,
           const int* __restrict__ uid, const int* __restrict__ iid,
           float* __restrict__ out) {
    int slot = blockIdx.x * 4 + (threadIdx.x >> 6);
    if (slot >= 2 * BATCH) return;
    int lane = threadIdx.x & 63;
    int grp = lane >> 4;
    int c = lane & 15;
    int isItem = slot >= BATCH;
    int b = isItem ? (slot - BATCH) : slot;
    int node = isItem ? (N_USERS + iid[b]) : uid[b];
    int4 ni = nodeinfo[node];
    float4 acc = gather_sum(g2, packed, ni.x, ni.y, grp, c);
#pragma unroll
    for (int off = 16; off < 64; off <<= 1) {
        acc.x += __shfl_xor(acc.x, off, 64);
        acc.y += __shfl_xor(acc.y, off, 64);
        acc.z += __shfl_xor(acc.z, off, 64);
        acc.w += __shfl_xor(acc.w, off, 64);
    }
    if (lane < 16) {
        const float* xb = isItem ? (ie + (size_t)(node - N_USERS) * DIM)
                                 : (ue + (size_t)node * DIM);
        float4 x = ((const float4*)xb)[c];
        ushort4 a1 = ((const ushort4*)(g1 + (size_t)node * DIM))[c];
        ushort4 a2 = ((const ushort4*)(g2 + (size_t)node * DIM))[c];
        float rn = __int_as_float(ni.w);
        float nm = __int_as_float(ni.z);
        float4 r;
        r.x = 0.25f * (x.x + rn * (bf2f(a1.x) + bf2f(a2.x)) + nm * acc.x);
        r.y = 0.25f * (x.y + rn * (bf2f(a1.y) + bf2f(a2.y)) + nm * acc.y);
        r.z = 0.25f * (x.z + rn * (bf2f(a1.z) + bf2f(a2.z)) + nm * acc.z);
        r.w = 0.25f * (x.w + rn * (bf2f(a1.w) + bf2f(a2.w)) + nm * acc.w);
        ((float4*)(out + (size_t)slot * DIM))[c] = r;
    }
}

// --- Launch ----------------------------------------------------------------

extern "C" void kernel_launch(void* const* d_in, const int* in_sizes, int n_in,
                              void* d_out, int out_size, void* d_ws, size_t ws_size,
                              hipStream_t stream) {
    const float* ue  = (const float*)d_in[0];
    const float* ie  = (const float*)d_in[1];
    const int*   ei  = (const int*)d_in[3];
    const int*   uid = (const int*)d_in[4];
    const int*   iid = (const int*)d_in[5];
    float* out = (float*)d_out;

    const int E  = in_sizes[2];     // 2,000,000 directed edges
    const int EH = E / 2;           // 1,000,000 undirected pairs
    const int* row = ei;            // first-half src = user ids
    const int* col = ei + E;        // first-half dst = item node ids

    const int nblk = (EH + PAIRS_PER_BLK - 1) / PAIRS_PER_BLK;   // 489

    // Workspace carve-up (256-B aligned), ~58 MB total.
    char* p = (char*)d_ws;
    size_t off = 0;
    auto carve = [&](size_t bytes) -> char* {
        char* r = p + off;
        off += (bytes + 255) & ~(size_t)255;
        return r;
    };
    const size_t nodeBf16 = (size_t)(N_NODES + 1) * DIM * sizeof(bf16_t); // +zero row
    bf16_t* gA       = (bf16_t*)carve(nodeBf16);
    bf16_t* gB       = (bf16_t*)carve(nodeBf16);
    int4*   nodeinfo = (int4*)carve((size_t)N_NODES * sizeof(int4));       // 2.4 MB
    int*    pos      = (int*)carve((size_t)nblk * (NB + 1) * sizeof(int)); // 1.15 MB
    int*    binned   = (int*)carve((size_t)nblk * STRIP * sizeof(int));    // 8 MB
    int*    packed   = (int*)carve((size_t)NB * CAP * sizeof(int));        // 19.2 MB
    (void)ws_size;

    // 1) Strip sort.
    lgcn_bin<<<nblk, 256, 0, stream>>>(row, col, pos, binned, EH);
    // 2) Per-bucket CSR + fused g0 init + zero rows.
    lgcn_build_csr<<<NB, 256, 0, stream>>>(pos, binned, nodeinfo, packed,
                                           ue, ie, gA, gB, nblk);
    // 3) Two full pulls (g1, g2), then fused batch-only layer 3 + epilogue.
    const int pullGrid = (N_NODES + 3) / 4;
    lgcn_pull<<<pullGrid, 256, 0, stream>>>(gA, nodeinfo, packed, gB);  // g1 = gB
    lgcn_pull<<<pullGrid, 256, 0, stream>>>(gB, nodeinfo, packed, gA);  // g2 = gA
    lgcn_final<<<(2 * BATCH + 3) / 4, 256, 0, stream>>>(
        ue, ie, gB, gA, nodeinfo, packed, uid, iid, out);
}

// Round 6
// 224.008 us; speedup vs baseline: 4.6320x; 1.0259x over previous
//
#include <hip/hip_runtime.h>

// LightGCN encoder on MI355X — round 13.
// Round 12 post-mortem: csr+init fusion saved ~0 -> dispatch overhead is
// small; the pull (2 x 48.5 us, 42% of wall) is the visible target. Its
// counters (28.5% HBM, 52% VALU, 68% occ — nothing saturated) say
// latency-bound: the packed->rows dependent chain isn't overlapped enough.
// This round: TWO independent nodes per wave (adjacent nodes; contiguous
// segments share packed/nodeinfo lines) -> ~8 row-loads in flight per wave,
// +12 VGPR. 32-bit gather offsets (saddr form). Per-node accumulation order
// bit-identical -> absmax must stay exactly 0.0078125.
// bin / csr / final unchanged (clean A/B on the pull counters).
#define N_USERS 100000
#define N_NODES 150000
#define DIM 64
#define BATCH 4096
#define BSHIFT 8
#define BUCKET 256
#define NB 586                 // ceil(150000 / 256) buckets
#define NBP 768                // padded bucket count for the 3-per-thread scan
#define PAIRS_PER_BLK 2048     // undirected pairs per binning block
#define STRIP 4096             // directed edges (words) per strip
#define CAPSHIFT 13
#define CAP (1 << CAPSHIFT)    // packed slots per bucket (max ~6.3K used)

typedef unsigned short bf16_t;

static __device__ __forceinline__ float bf2f(bf16_t h) {
    return __uint_as_float(((unsigned)h) << 16);
}
static __device__ __forceinline__ bf16_t f2bf(float f) {  // round-nearest-even
    unsigned u = __float_as_uint(f);
    return (bf16_t)((u + 0x7FFFu + ((u >> 16) & 1u)) >> 16);
}

// --- Strip sort: LDS counting-sort of 4096 directed edges by bucket --------
// binned word = (local_dst[8b]<<18)|src. pos[k*(NB+1)+b] = run start of
// bucket b in strip k; pos[k*(NB+1)+NB] = edge count of strip k.
__global__ void __launch_bounds__(256)
lgcn_bin(const int* __restrict__ row, const int* __restrict__ col,
         int* __restrict__ pos, int* __restrict__ binned, int EH) {
    __shared__ int cnt[NBP];
    __shared__ int sA[256], sB[256];
    __shared__ int base[NB + 2];
    __shared__ int stage[STRIP];
    int tid = threadIdx.x;
    int k = blockIdx.x;
    cnt[tid] = 0; cnt[tid + 256] = 0; cnt[tid + 512] = 0;
    __syncthreads();
    int e0 = k * PAIRS_PER_BLK;
    int e1 = min(EH, e0 + PAIRS_PER_BLK);
    int n = e1 - e0;                           // pairs (multiple of 4)
    int nq = n >> 2;
    const int4* r4 = (const int4*)(row + e0);
    const int4* c4 = (const int4*)(col + e0);
    for (int q = tid; q < nq; q += 256) {
        int4 r = r4[q]; int4 c = c4[q];
        atomicAdd(&cnt[r.x >> BSHIFT], 1); atomicAdd(&cnt[c.x >> BSHIFT], 1);
        atomicAdd(&cnt[r.y >> BSHIFT], 1); atomicAdd(&cnt[c.y >> BSHIFT], 1);
        atomicAdd(&cnt[r.z >> BSHIFT], 1); atomicAdd(&cnt[c.z >> BSHIFT], 1);
        atomicAdd(&cnt[r.w >> BSHIFT], 1); atomicAdd(&cnt[c.w >> BSHIFT], 1);
    }
    __syncthreads();
    // Exclusive scan over NBP buckets, 3 per thread.
    int c0 = cnt[3 * tid], c1 = cnt[3 * tid + 1], c2 = cnt[3 * tid + 2];
    int s = c0 + c1 + c2;
    sA[tid] = s;
    __syncthreads();
    int* c_ = sA; int* n_ = sB;
    for (int off = 1; off < 256; off <<= 1) {
        n_[tid] = (tid >= off) ? c_[tid] + c_[tid - off] : c_[tid];
        __syncthreads();
        int* t = c_; c_ = n_; n_ = t;
    }
    int excl = c_[tid] - s;
    if (3 * tid     <= NB) base[3 * tid]     = excl;
    if (3 * tid + 1 <= NB) base[3 * tid + 1] = excl + c0;
    if (3 * tid + 2 <= NB) base[3 * tid + 2] = excl + c0 + c1;
    __syncthreads();
    // pos table (coalesced) + LDS cursors (reuse cnt).
    for (int i = tid; i <= NB; i += 256) {
        pos[k * (NB + 1) + i] = base[i];
        cnt[i] = base[i];
    }
    __syncthreads();
    // LDS scatter (re-read pairs; L2-hot).
    for (int q = tid; q < nq; q += 256) {
        int4 r = r4[q]; int4 c = c4[q];
        int rr[4] = { r.x, r.y, r.z, r.w };
        int cc[4] = { c.x, c.y, c.z, c.w };
#pragma unroll
        for (int j = 0; j < 4; ++j) {
            int p1 = atomicAdd(&cnt[cc[j] >> BSHIFT], 1);
            stage[p1] = ((cc[j] & (BUCKET - 1)) << 18) | rr[j];
            int p2 = atomicAdd(&cnt[rr[j] >> BSHIFT], 1);
            stage[p2] = ((rr[j] & (BUCKET - 1)) << 18) | cc[j];
        }
    }
    __syncthreads();
    // Coalesced strip write-out.
    int m4 = (2 * n) >> 2;
    int4* dst = (int4*)(binned + k * STRIP);
    const int4* st4 = (const int4*)stage;
    for (int j = tid; j < m4; j += 256) dst[j] = st4[j];
}

// --- Per-bucket padded CSR + fused g0 init ---------------------------------
// Node segments padded to multiple of 4; pad slots = N_NODES (zero row).
// nodeinfo = {start, deg, bits(1/sqrt(da)), bits(sqrt(da))}.
// Also writes g0 = norm*x (bf16) for this bucket's nodes + zero rows (blk 0).
__global__ void __launch_bounds__(256)
lgcn_build_csr(const int* __restrict__ pos, const int* __restrict__ binned,
               int4* __restrict__ nodeinfo, int* __restrict__ packed,
               const float* __restrict__ ue, const float* __restrict__ ie,
               bf16_t* __restrict__ g0, bf16_t* __restrict__ g1, int nblk) {
    __shared__ int stage[CAP];     // gathered edges of this bucket
    __shared__ int sorted[CAP];    // node-sorted + padded
    __shared__ int sA[256], sB[256];
    __shared__ int hist[256], cur[256];
    int b = blockIdx.x;
    int tid = threadIdx.x;
    // Runs for strips tid and tid+256.
    int a0 = 0, l0 = 0, a1 = 0, l1 = 0;
    if (tid < nblk) {
        const int* pk = pos + tid * (NB + 1) + b;
        a0 = pk[0]; l0 = pk[1] - a0;
    }
    if (tid + 256 < nblk) {
        const int* pk = pos + (tid + 256) * (NB + 1) + b;
        a1 = pk[0]; l1 = pk[1] - a1;
    }
    int u = l0 + l1;
    sA[tid] = u;
    __syncthreads();
    int* c_ = sA; int* n_ = sB;
    for (int off = 1; off < 256; off <<= 1) {
        n_[tid] = (tid >= off) ? c_[tid] + c_[tid - off] : c_[tid];
        __syncthreads();
        int* t = c_; c_ = n_; n_ = t;
    }
    int myBase = c_[tid] - u;
    int Eb = c_[255];
    __syncthreads();
    // Gather runs into stage (short scattered reads, x4 unrolled for MLP).
    {
        const int* s0 = binned + tid * STRIP + a0;
        int i = 0;
        for (; i + 4 <= l0; i += 4) {
            int w0 = s0[i], w1 = s0[i + 1], w2 = s0[i + 2], w3 = s0[i + 3];
            stage[myBase + i] = w0;     stage[myBase + i + 1] = w1;
            stage[myBase + i + 2] = w2; stage[myBase + i + 3] = w3;
        }
        for (; i < l0; ++i) stage[myBase + i] = s0[i];
        const int* s1 = binned + (tid + 256) * STRIP + a1;
        int bb = myBase + l0;
        i = 0;
        for (; i + 4 <= l1; i += 4) {
            int w0 = s1[i], w1 = s1[i + 1], w2 = s1[i + 2], w3 = s1[i + 3];
            stage[bb + i] = w0;     stage[bb + i + 1] = w1;
            stage[bb + i + 2] = w2; stage[bb + i + 3] = w3;
        }
        for (; i < l1; ++i) stage[bb + i] = s1[i];
    }
    hist[tid] = 0;
    __syncthreads();
    for (int j = tid; j < Eb; j += 256)
        atomicAdd(&hist[stage[j] >> 18], 1);
    __syncthreads();
    int deg = hist[tid];
    int degp = (deg + 3) & ~3;               // padded segment length
    sA[tid] = degp;
    __syncthreads();
    int* c2 = sA; int* n2 = sB;
    for (int off = 1; off < 256; off <<= 1) {
        n2[tid] = (tid >= off) ? c2[tid] + c2[tid - off] : c2[tid];
        __syncthreads();
        int* t = c2; c2 = n2; n2 = t;
    }
    int startLoc = c2[tid] - degp;           // local, int4-aligned
    int totPad = c2[255];
    cur[tid] = startLoc;
    int gstart = (b << CAPSHIFT) + startLoc;
    int node = (b << BSHIFT) + tid;
    float da = (deg == 0) ? 1.0f : (float)deg;
    float sq = sqrtf(da);
    float nm = 1.0f / sq;
    if (node < N_NODES) {
        int4 ni;
        ni.x = gstart;
        ni.y = deg;
        ni.z = __float_as_int(nm);
        ni.w = __float_as_int(sq);
        nodeinfo[node] = ni;
    }
    __syncthreads();                          // all hist reads done
    hist[tid] = __float_as_int(nm);           // reuse hist as norm table
    // Prefill (covers pad slots with the zero row).
    for (int j = tid; j < totPad; j += 256) sorted[j] = N_NODES;
    __syncthreads();
    for (int j = tid; j < Eb; j += 256) {
        int w = stage[j];
        int p = atomicAdd(&cur[w >> 18], 1);  // LDS atomic
        sorted[p] = w & 0x3FFFF;
    }
    __syncthreads();
    // Coalesced bucket-region write-out.
    int4* dst = (int4*)(packed + (b << CAPSHIFT));
    const int4* s4 = (const int4*)sorted;
    for (int j = tid; j < (totPad >> 2); j += 256) dst[j] = s4[j];
    // --- Fused g0 init for this bucket's nodes (flat chunk range is
    // contiguous: t = b*4096 + i, i in [0, nloc*16)). -----------------------
    int firstNode = b << BSHIFT;
    int nloc = min(BUCKET, N_NODES - firstNode);
    const int nU16 = N_USERS * (DIM / 4);
    int t0 = firstNode * (DIM / 4);
    for (int i = tid; i < nloc * (DIM / 4); i += 256) {
        int t = t0 + i;
        float4 x = (t < nU16) ? ((const float4*)ue)[t]
                              : ((const float4*)ie)[t - nU16];
        float nrm = __int_as_float(hist[i >> 4]);
        ushort4 o;
        o.x = f2bf(x.x * nrm); o.y = f2bf(x.y * nrm);
        o.z = f2bf(x.z * nrm); o.w = f2bf(x.w * nrm);
        ((ushort4*)g0)[t] = o;
    }
    if (b == 0 && tid < 32) {                 // zero rows in both buffers
        const int nT = N_NODES * (DIM / 4);
        if (tid < 16) ((ushort4*)g0)[nT + tid] = make_ushort4(0, 0, 0, 0);
        else          ((ushort4*)g1)[nT + tid - 16] = make_ushort4(0, 0, 0, 0);
    }
}

// --- Propagation -----------------------------------------------------------

// Accumulate 4 rows (one int4 of edge ids) into acc.
static __device__ __forceinline__ void
acc_quad(const bf16_t* __restrict__ g, int4 e, int c, float4& acc) {
    ushort4 v0 = ((const ushort4*)(g + ((unsigned)e.x << 6)))[c];
    ushort4 v1 = ((const ushort4*)(g + ((unsigned)e.y << 6)))[c];
    ushort4 v2 = ((const ushort4*)(g + ((unsigned)e.z << 6)))[c];
    ushort4 v3 = ((const ushort4*)(g + ((unsigned)e.w << 6)))[c];
    acc.x += bf2f(v0.x); acc.y += bf2f(v0.y);
    acc.z += bf2f(v0.z); acc.w += bf2f(v0.w);
    acc.x += bf2f(v1.x); acc.y += bf2f(v1.y);
    acc.z += bf2f(v1.z); acc.w += bf2f(v1.w);
    acc.x += bf2f(v2.x); acc.y += bf2f(v2.y);
    acc.z += bf2f(v2.z); acc.w += bf2f(v2.w);
    acc.x += bf2f(v3.x); acc.y += bf2f(v3.y);
    acc.z += bf2f(v3.z); acc.w += bf2f(v3.w);
}

// Gather core: 16-lane group sums g rows for edges [start, start+deg).
// Pad slots point at the zero row -> plain adds, no clamps, no weights.
static __device__ __forceinline__ float4
gather_sum(const bf16_t* __restrict__ g, const int* __restrict__ packed,
           int start, int deg, int grp, int c) {
    float4 acc = make_float4(0.f, 0.f, 0.f, 0.f);
    for (int o = 4 * grp; o < deg; o += 16) {
        int4 e4 = *(const int4*)(packed + start + o);  // 16-B aligned
        acc_quad(g, e4, c, acc);
    }
    return acc;
}

static __device__ __forceinline__ void
wave_reduce(float4& acc) {
#pragma unroll
    for (int off = 16; off < 64; off <<= 1) {
        acc.x += __shfl_xor(acc.x, off, 64);
        acc.y += __shfl_xor(acc.y, off, 64);
        acc.z += __shfl_xor(acc.z, off, 64);
        acc.w += __shfl_xor(acc.w, off, 64);
    }
}

// Full pull, TWO adjacent nodes per wave (independent gather streams for
// memory-level parallelism): gn[n] = bf16( norm[n]^2 * sum g[src] ).
__global__ void __launch_bounds__(256)
lgcn_pull(const bf16_t* __restrict__ g, const int4* __restrict__ nodeinfo,
          const int* __restrict__ packed, bf16_t* __restrict__ gn) {
    int gw = blockIdx.x * 4 + (threadIdx.x >> 6);
    int n0 = gw * 2;
    if (n0 >= N_NODES) return;
    int n1 = n0 + 1;                        // N_NODES even -> always valid
    int lane = threadIdx.x & 63;
    int grp = lane >> 4;
    int c = lane & 15;
    int4 ni0 = nodeinfo[n0];
    int4 ni1 = nodeinfo[n1];
    int s0 = ni0.x, d0 = ni0.y;
    int s1 = ni1.x, d1 = ni1.y;
    float4 a0 = make_float4(0.f, 0.f, 0.f, 0.f);
    float4 a1 = make_float4(0.f, 0.f, 0.f, 0.f);
    int dm = max(d0, d1);
    for (int o = 4 * grp; o < dm; o += 16) {
        if (o < d0) {
            int4 e4 = *(const int4*)(packed + s0 + o);
            acc_quad(g, e4, c, a0);
        }
        if (o < d1) {
            int4 e4 = *(const int4*)(packed + s1 + o);
            acc_quad(g, e4, c, a1);
        }
    }
    wave_reduce(a0);
    wave_reduce(a1);
    if (lane < 16) {
        float m0 = __int_as_float(ni0.z);
        float m1 = __int_as_float(ni1.z);
        float q0 = m0 * m0, q1 = m1 * m1;
        ushort4 o0, o1;
        o0.x = f2bf(a0.x * q0); o0.y = f2bf(a0.y * q0);
        o0.z = f2bf(a0.z * q0); o0.w = f2bf(a0.w * q0);
        o1.x = f2bf(a1.x * q1); o1.y = f2bf(a1.y * q1);
        o1.z = f2bf(a1.z * q1); o1.w = f2bf(a1.w * q1);
        ((ushort4*)(gn + ((unsigned)n0 << 6)))[c] = o0;
        ((ushort4*)(gn + ((unsigned)n1 << 6)))[c] = o1;
    }
}

// Fused layer-3 + epilogue, batch nodes only:
// out[slot] = 0.25*( x[n] + rn*g1[n] + rn*g2[n] + nm*sum_{s in N(n)} g2[s] ).
__global__ void __launch_bounds__(256)
lgcn_final(const float* __restrict__ ue, const float* __restrict__ ie,
           const bf16_t* __restrict__ g1, const bf16_t* __restrict__ g2,
           const int4* __restrict__ nodeinfo, const int* __restrict__ packed,
           const int* __restrict__ uid, const int* __restrict__ iid,
           float* __restrict__ out) {
    int slot = blockIdx.x * 4 + (threadIdx.x >> 6);
    if (slot >= 2 * BATCH) return;
    int lane = threadIdx.x & 63;
    int grp = lane >> 4;
    int c = lane & 15;
    int isItem = slot >= BATCH;
    int b = isItem ? (slot - BATCH) : slot;
    int node = isItem ? (N_USERS + iid[b]) : uid[b];
    int4 ni = nodeinfo[node];
    float4 acc = gather_sum(g2, packed, ni.x, ni.y, grp, c);
    wave_reduce(acc);
    if (lane < 16) {
        const float* xb = isItem ? (ie + (size_t)(node - N_USERS) * DIM)
                                 : (ue + (size_t)node * DIM);
        float4 x = ((const float4*)xb)[c];
        ushort4 a1 = ((const ushort4*)(g1 + ((unsigned)node << 6)))[c];
        ushort4 a2 = ((const ushort4*)(g2 + ((unsigned)node << 6)))[c];
        float rn = __int_as_float(ni.w);
        float nm = __int_as_float(ni.z);
        float4 r;
        r.x = 0.25f * (x.x + rn * (bf2f(a1.x) + bf2f(a2.x)) + nm * acc.x);
        r.y = 0.25f * (x.y + rn * (bf2f(a1.y) + bf2f(a2.y)) + nm * acc.y);
        r.z = 0.25f * (x.z + rn * (bf2f(a1.z) + bf2f(a2.z)) + nm * acc.z);
        r.w = 0.25f * (x.w + rn * (bf2f(a1.w) + bf2f(a2.w)) + nm * acc.w);
        ((float4*)(out + (size_t)slot * DIM))[c] = r;
    }
}

// --- Launch ----------------------------------------------------------------

extern "C" void kernel_launch(void* const* d_in, const int* in_sizes, int n_in,
                              void* d_out, int out_size, void* d_ws, size_t ws_size,
                              hipStream_t stream) {
    const float* ue  = (const float*)d_in[0];
    const float* ie  = (const float*)d_in[1];
    const int*   ei  = (const int*)d_in[3];
    const int*   uid = (const int*)d_in[4];
    const int*   iid = (const int*)d_in[5];
    float* out = (float*)d_out;

    const int E  = in_sizes[2];     // 2,000,000 directed edges
    const int EH = E / 2;           // 1,000,000 undirected pairs
    const int* row = ei;            // first-half src = user ids
    const int* col = ei + E;        // first-half dst = item node ids

    const int nblk = (EH + PAIRS_PER_BLK - 1) / PAIRS_PER_BLK;   // 489

    // Workspace carve-up (256-B aligned), ~58 MB total.
    char* p = (char*)d_ws;
    size_t off = 0;
    auto carve = [&](size_t bytes) -> char* {
        char* r = p + off;
        off += (bytes + 255) & ~(size_t)255;
        return r;
    };
    const size_t nodeBf16 = (size_t)(N_NODES + 1) * DIM * sizeof(bf16_t); // +zero row
    bf16_t* gA       = (bf16_t*)carve(nodeBf16);
    bf16_t* gB       = (bf16_t*)carve(nodeBf16);
    int4*   nodeinfo = (int4*)carve((size_t)N_NODES * sizeof(int4));       // 2.4 MB
    int*    pos      = (int*)carve((size_t)nblk * (NB + 1) * sizeof(int)); // 1.15 MB
    int*    binned   = (int*)carve((size_t)nblk * STRIP * sizeof(int));    // 8 MB
    int*    packed   = (int*)carve((size_t)NB * CAP * sizeof(int));        // 19.2 MB
    (void)ws_size;

    // 1) Strip sort.
    lgcn_bin<<<nblk, 256, 0, stream>>>(row, col, pos, binned, EH);
    // 2) Per-bucket CSR + fused g0 init + zero rows.
    lgcn_build_csr<<<NB, 256, 0, stream>>>(pos, binned, nodeinfo, packed,
                                           ue, ie, gA, gB, nblk);
    // 3) Two full pulls (2 nodes/wave), then fused batch-only epilogue.
    const int pullGrid = (N_NODES / 2 + 3) / 4;    // 18750
    lgcn_pull<<<pullGrid, 256, 0, stream>>>(gA, nodeinfo, packed, gB);  // g1 = gB
    lgcn_pull<<<pullGrid, 256, 0, stream>>>(gB, nodeinfo, packed, gA);  // g2 = gA
    lgcn_final<<<(2 * BATCH + 3) / 4, 256, 0, stream>>>(
        ue, ie, gB, gA, nodeinfo, packed, uid, iid, out);
}

// Round 7
// 223.183 us; speedup vs baseline: 4.6491x; 1.0037x over previous
//
#include <hip/hip_runtime.h>

// LightGCN encoder on MI355X — round 14.
// Round 13 post-mortem: pull spends ~13 VALU insts/edge, of which ~9 are
// 64-bit vector address math for the gathered rows (v_lshl_add_u64 chains);
// only ~4 are real accumulate work. Fix: lane=dim gather (DIM == wave64).
//   - one node per wave; lane l owns dimension l; no cross-lane reduce
//   - segment start/deg wave-uniform (readfirstlane) -> edge quads via
//     s_load_dwordx4 on the SCALAR pipe
//   - row base = SALU (s_lshl/s_add); row read = global_load_ushort saddr
//     form with loop-invariant lane*2 voffset -> zero per-edge VALU addr
//   - 8-edge unroll -> 8 independent row loads in flight per wave
//   - full-wave 128-B coalesced store
// lgcn_final rewritten in the same style. bin / csr unchanged (proven).
#define N_USERS 100000
#define N_NODES 150000
#define DIM 64
#define BATCH 4096
#define BSHIFT 8
#define BUCKET 256
#define NB 586                 // ceil(150000 / 256) buckets
#define NBP 768                // padded bucket count for the 3-per-thread scan
#define PAIRS_PER_BLK 2048     // undirected pairs per binning block
#define STRIP 4096             // directed edges (words) per strip
#define CAPSHIFT 13
#define CAP (1 << CAPSHIFT)    // packed slots per bucket (max ~6.3K used)

typedef unsigned short bf16_t;

static __device__ __forceinline__ float bf2f(bf16_t h) {
    return __uint_as_float(((unsigned)h) << 16);
}
static __device__ __forceinline__ bf16_t f2bf(float f) {  // round-nearest-even
    unsigned u = __float_as_uint(f);
    return (bf16_t)((u + 0x7FFFu + ((u >> 16) & 1u)) >> 16);
}

// --- Strip sort: LDS counting-sort of 4096 directed edges by bucket --------
// binned word = (local_dst[8b]<<18)|src. pos[k*(NB+1)+b] = run start of
// bucket b in strip k; pos[k*(NB+1)+NB] = edge count of strip k.
__global__ void __launch_bounds__(256)
lgcn_bin(const int* __restrict__ row, const int* __restrict__ col,
         int* __restrict__ pos, int* __restrict__ binned, int EH) {
    __shared__ int cnt[NBP];
    __shared__ int sA[256], sB[256];
    __shared__ int base[NB + 2];
    __shared__ int stage[STRIP];
    int tid = threadIdx.x;
    int k = blockIdx.x;
    cnt[tid] = 0; cnt[tid + 256] = 0; cnt[tid + 512] = 0;
    __syncthreads();
    int e0 = k * PAIRS_PER_BLK;
    int e1 = min(EH, e0 + PAIRS_PER_BLK);
    int n = e1 - e0;                           // pairs (multiple of 4)
    int nq = n >> 2;
    const int4* r4 = (const int4*)(row + e0);
    const int4* c4 = (const int4*)(col + e0);
    for (int q = tid; q < nq; q += 256) {
        int4 r = r4[q]; int4 c = c4[q];
        atomicAdd(&cnt[r.x >> BSHIFT], 1); atomicAdd(&cnt[c.x >> BSHIFT], 1);
        atomicAdd(&cnt[r.y >> BSHIFT], 1); atomicAdd(&cnt[c.y >> BSHIFT], 1);
        atomicAdd(&cnt[r.z >> BSHIFT], 1); atomicAdd(&cnt[c.z >> BSHIFT], 1);
        atomicAdd(&cnt[r.w >> BSHIFT], 1); atomicAdd(&cnt[c.w >> BSHIFT], 1);
    }
    __syncthreads();
    // Exclusive scan over NBP buckets, 3 per thread.
    int c0 = cnt[3 * tid], c1 = cnt[3 * tid + 1], c2 = cnt[3 * tid + 2];
    int s = c0 + c1 + c2;
    sA[tid] = s;
    __syncthreads();
    int* c_ = sA; int* n_ = sB;
    for (int off = 1; off < 256; off <<= 1) {
        n_[tid] = (tid >= off) ? c_[tid] + c_[tid - off] : c_[tid];
        __syncthreads();
        int* t = c_; c_ = n_; n_ = t;
    }
    int excl = c_[tid] - s;
    if (3 * tid     <= NB) base[3 * tid]     = excl;
    if (3 * tid + 1 <= NB) base[3 * tid + 1] = excl + c0;
    if (3 * tid + 2 <= NB) base[3 * tid + 2] = excl + c0 + c1;
    __syncthreads();
    // pos table (coalesced) + LDS cursors (reuse cnt).
    for (int i = tid; i <= NB; i += 256) {
        pos[k * (NB + 1) + i] = base[i];
        cnt[i] = base[i];
    }
    __syncthreads();
    // LDS scatter (re-read pairs; L2-hot).
    for (int q = tid; q < nq; q += 256) {
        int4 r = r4[q]; int4 c = c4[q];
        int rr[4] = { r.x, r.y, r.z, r.w };
        int cc[4] = { c.x, c.y, c.z, c.w };
#pragma unroll
        for (int j = 0; j < 4; ++j) {
            int p1 = atomicAdd(&cnt[cc[j] >> BSHIFT], 1);
            stage[p1] = ((cc[j] & (BUCKET - 1)) << 18) | rr[j];
            int p2 = atomicAdd(&cnt[rr[j] >> BSHIFT], 1);
            stage[p2] = ((rr[j] & (BUCKET - 1)) << 18) | cc[j];
        }
    }
    __syncthreads();
    // Coalesced strip write-out.
    int m4 = (2 * n) >> 2;
    int4* dst = (int4*)(binned + k * STRIP);
    const int4* st4 = (const int4*)stage;
    for (int j = tid; j < m4; j += 256) dst[j] = st4[j];
}

// --- Per-bucket padded CSR + fused g0 init ---------------------------------
// Node segments padded to multiple of 4; pad slots = N_NODES (zero row).
// nodeinfo = {start, deg, bits(1/sqrt(da)), bits(sqrt(da))}.
// Also writes g0 = norm*x (bf16) for this bucket's nodes + zero rows (blk 0).
__global__ void __launch_bounds__(256)
lgcn_build_csr(const int* __restrict__ pos, const int* __restrict__ binned,
               int4* __restrict__ nodeinfo, int* __restrict__ packed,
               const float* __restrict__ ue, const float* __restrict__ ie,
               bf16_t* __restrict__ g0, bf16_t* __restrict__ g1, int nblk) {
    __shared__ int stage[CAP];     // gathered edges of this bucket
    __shared__ int sorted[CAP];    // node-sorted + padded
    __shared__ int sA[256], sB[256];
    __shared__ int hist[256], cur[256];
    int b = blockIdx.x;
    int tid = threadIdx.x;
    // Runs for strips tid and tid+256.
    int a0 = 0, l0 = 0, a1 = 0, l1 = 0;
    if (tid < nblk) {
        const int* pk = pos + tid * (NB + 1) + b;
        a0 = pk[0]; l0 = pk[1] - a0;
    }
    if (tid + 256 < nblk) {
        const int* pk = pos + (tid + 256) * (NB + 1) + b;
        a1 = pk[0]; l1 = pk[1] - a1;
    }
    int u = l0 + l1;
    sA[tid] = u;
    __syncthreads();
    int* c_ = sA; int* n_ = sB;
    for (int off = 1; off < 256; off <<= 1) {
        n_[tid] = (tid >= off) ? c_[tid] + c_[tid - off] : c_[tid];
        __syncthreads();
        int* t = c_; c_ = n_; n_ = t;
    }
    int myBase = c_[tid] - u;
    int Eb = c_[255];
    __syncthreads();
    // Gather runs into stage (short scattered reads, x4 unrolled for MLP).
    {
        const int* s0 = binned + tid * STRIP + a0;
        int i = 0;
        for (; i + 4 <= l0; i += 4) {
            int w0 = s0[i], w1 = s0[i + 1], w2 = s0[i + 2], w3 = s0[i + 3];
            stage[myBase + i] = w0;     stage[myBase + i + 1] = w1;
            stage[myBase + i + 2] = w2; stage[myBase + i + 3] = w3;
        }
        for (; i < l0; ++i) stage[myBase + i] = s0[i];
        const int* s1 = binned + (tid + 256) * STRIP + a1;
        int bb = myBase + l0;
        i = 0;
        for (; i + 4 <= l1; i += 4) {
            int w0 = s1[i], w1 = s1[i + 1], w2 = s1[i + 2], w3 = s1[i + 3];
            stage[bb + i] = w0;     stage[bb + i + 1] = w1;
            stage[bb + i + 2] = w2; stage[bb + i + 3] = w3;
        }
        for (; i < l1; ++i) stage[bb + i] = s1[i];
    }
    hist[tid] = 0;
    __syncthreads();
    for (int j = tid; j < Eb; j += 256)
        atomicAdd(&hist[stage[j] >> 18], 1);
    __syncthreads();
    int deg = hist[tid];
    int degp = (deg + 3) & ~3;               // padded segment length
    sA[tid] = degp;
    __syncthreads();
    int* c2 = sA; int* n2 = sB;
    for (int off = 1; off < 256; off <<= 1) {
        n2[tid] = (tid >= off) ? c2[tid] + c2[tid - off] : c2[tid];
        __syncthreads();
        int* t = c2; c2 = n2; n2 = t;
    }
    int startLoc = c2[tid] - degp;           // local, int4-aligned
    int totPad = c2[255];
    cur[tid] = startLoc;
    int gstart = (b << CAPSHIFT) + startLoc;
    int node = (b << BSHIFT) + tid;
    float da = (deg == 0) ? 1.0f : (float)deg;
    float sq = sqrtf(da);
    float nm = 1.0f / sq;
    if (node < N_NODES) {
        int4 ni;
        ni.x = gstart;
        ni.y = deg;
        ni.z = __float_as_int(nm);
        ni.w = __float_as_int(sq);
        nodeinfo[node] = ni;
    }
    __syncthreads();                          // all hist reads done
    hist[tid] = __float_as_int(nm);           // reuse hist as norm table
    // Prefill (covers pad slots with the zero row).
    for (int j = tid; j < totPad; j += 256) sorted[j] = N_NODES;
    __syncthreads();
    for (int j = tid; j < Eb; j += 256) {
        int w = stage[j];
        int p = atomicAdd(&cur[w >> 18], 1);  // LDS atomic
        sorted[p] = w & 0x3FFFF;
    }
    __syncthreads();
    // Coalesced bucket-region write-out.
    int4* dst = (int4*)(packed + (b << CAPSHIFT));
    const int4* s4 = (const int4*)sorted;
    for (int j = tid; j < (totPad >> 2); j += 256) dst[j] = s4[j];
    // --- Fused g0 init for this bucket's nodes (flat chunk range is
    // contiguous: t = b*4096 + i, i in [0, nloc*16)). -----------------------
    int firstNode = b << BSHIFT;
    int nloc = min(BUCKET, N_NODES - firstNode);
    const int nU16 = N_USERS * (DIM / 4);
    int t0 = firstNode * (DIM / 4);
    for (int i = tid; i < nloc * (DIM / 4); i += 256) {
        int t = t0 + i;
        float4 x = (t < nU16) ? ((const float4*)ue)[t]
                              : ((const float4*)ie)[t - nU16];
        float nrm = __int_as_float(hist[i >> 4]);
        ushort4 o;
        o.x = f2bf(x.x * nrm); o.y = f2bf(x.y * nrm);
        o.z = f2bf(x.z * nrm); o.w = f2bf(x.w * nrm);
        ((ushort4*)g0)[t] = o;
    }
    if (b == 0 && tid < 32) {                 // zero rows in both buffers
        const int nT = N_NODES * (DIM / 4);
        if (tid < 16) ((ushort4*)g0)[nT + tid] = make_ushort4(0, 0, 0, 0);
        else          ((ushort4*)g1)[nT + tid - 16] = make_ushort4(0, 0, 0, 0);
    }
}

// --- Propagation (lane = dim) ----------------------------------------------

// Sum rows of g for edges [su, su+dp) into the per-lane accumulator.
// su/dp are wave-uniform SGPRs; edge quads come via scalar loads; each row
// read is saddr-form global_load_ushort with loop-invariant lane offset.
static __device__ __forceinline__ float
gather_lane(const bf16_t* __restrict__ g, const int* __restrict__ packed,
            int su, int dp, int lane) {
    float acc = 0.f;
    const int4* p4 = (const int4*)(packed + su);
    int k = 0;
    for (; k + 8 <= dp; k += 8) {            // 8 independent row loads
        int4 ea = p4[k >> 2];
        int4 eb = p4[(k >> 2) + 1];
        const bf16_t* r0 = g + ((unsigned)ea.x << 6);
        const bf16_t* r1 = g + ((unsigned)ea.y << 6);
        const bf16_t* r2 = g + ((unsigned)ea.z << 6);
        const bf16_t* r3 = g + ((unsigned)ea.w << 6);
        const bf16_t* r4 = g + ((unsigned)eb.x << 6);
        const bf16_t* r5 = g + ((unsigned)eb.y << 6);
        const bf16_t* r6 = g + ((unsigned)eb.z << 6);
        const bf16_t* r7 = g + ((unsigned)eb.w << 6);
        float v0 = bf2f(r0[lane]); float v1 = bf2f(r1[lane]);
        float v2 = bf2f(r2[lane]); float v3 = bf2f(r3[lane]);
        float v4 = bf2f(r4[lane]); float v5 = bf2f(r5[lane]);
        float v6 = bf2f(r6[lane]); float v7 = bf2f(r7[lane]);
        acc += ((v0 + v1) + (v2 + v3)) + ((v4 + v5) + (v6 + v7));
    }
    if (k < dp) {                            // tail quad (dp % 8 == 4)
        int4 ea = p4[k >> 2];
        const bf16_t* r0 = g + ((unsigned)ea.x << 6);
        const bf16_t* r1 = g + ((unsigned)ea.y << 6);
        const bf16_t* r2 = g + ((unsigned)ea.z << 6);
        const bf16_t* r3 = g + ((unsigned)ea.w << 6);
        float v0 = bf2f(r0[lane]); float v1 = bf2f(r1[lane]);
        float v2 = bf2f(r2[lane]); float v3 = bf2f(r3[lane]);
        acc += (v0 + v1) + (v2 + v3);
    }
    return acc;
}

// Full pull: gn[n] = bf16( norm[n]^2 * sum_{s in N(n)} g[s] ). One node/wave.
__global__ void __launch_bounds__(256)
lgcn_pull(const bf16_t* __restrict__ g, const int4* __restrict__ nodeinfo,
          const int* __restrict__ packed, bf16_t* __restrict__ gn) {
    int n = blockIdx.x * 4 + (threadIdx.x >> 6);
    if (n >= N_NODES) return;
    n = __builtin_amdgcn_readfirstlane(n);
    int lane = threadIdx.x & 63;
    int4 ni = nodeinfo[n];
    int su = __builtin_amdgcn_readfirstlane(ni.x);
    int du = __builtin_amdgcn_readfirstlane(ni.y);
    int dp = (du + 3) & ~3;
    float acc = gather_lane(g, packed, su, dp, lane);
    float nm = __int_as_float(ni.z);
    gn[((unsigned)n << 6) + lane] = f2bf(acc * nm * nm);
}

// Fused layer-3 + epilogue, batch nodes only (lane = dim):
// out[slot] = 0.25*( x[n] + rn*g1[n] + rn*g2[n] + nm*sum_{s in N(n)} g2[s] ).
__global__ void __launch_bounds__(256)
lgcn_final(const float* __restrict__ ue, const float* __restrict__ ie,
           const bf16_t* __restrict__ g1, const bf16_t* __restrict__ g2,
           const int4* __restrict__ nodeinfo, const int* __restrict__ packed,
           const int* __restrict__ uid, const int* __restrict__ iid,
           float* __restrict__ out) {
    int slot = blockIdx.x * 4 + (threadIdx.x >> 6);
    if (slot >= 2 * BATCH) return;
    slot = __builtin_amdgcn_readfirstlane(slot);
    int lane = threadIdx.x & 63;
    int isItem = slot >= BATCH;
    int b = isItem ? (slot - BATCH) : slot;
    int node = isItem ? (N_USERS + iid[b]) : uid[b];
    node = __builtin_amdgcn_readfirstlane(node);
    int4 ni = nodeinfo[node];
    int su = __builtin_amdgcn_readfirstlane(ni.x);
    int du = __builtin_amdgcn_readfirstlane(ni.y);
    int dp = (du + 3) & ~3;
    float acc = gather_lane(g2, packed, su, dp, lane);
    const float* xb = isItem ? (ie + ((unsigned)(node - N_USERS) << 6))
                             : (ue + ((unsigned)node << 6));
    float x = xb[lane];
    float a1 = bf2f(g1[((unsigned)node << 6) + lane]);
    float a2 = bf2f(g2[((unsigned)node << 6) + lane]);
    float rn = __int_as_float(ni.w);
    float nm = __int_as_float(ni.z);
    out[((unsigned)slot << 6) + lane] = 0.25f * (x + rn * (a1 + a2) + nm * acc);
}

// --- Launch ----------------------------------------------------------------

extern "C" void kernel_launch(void* const* d_in, const int* in_sizes, int n_in,
                              void* d_out, int out_size, void* d_ws, size_t ws_size,
                              hipStream_t stream) {
    const float* ue  = (const float*)d_in[0];
    const float* ie  = (const float*)d_in[1];
    const int*   ei  = (const int*)d_in[3];
    const int*   uid = (const int*)d_in[4];
    const int*   iid = (const int*)d_in[5];
    float* out = (float*)d_out;

    const int E  = in_sizes[2];     // 2,000,000 directed edges
    const int EH = E / 2;           // 1,000,000 undirected pairs
    const int* row = ei;            // first-half src = user ids
    const int* col = ei + E;        // first-half dst = item node ids

    const int nblk = (EH + PAIRS_PER_BLK - 1) / PAIRS_PER_BLK;   // 489

    // Workspace carve-up (256-B aligned), ~58 MB total.
    char* p = (char*)d_ws;
    size_t off = 0;
    auto carve = [&](size_t bytes) -> char* {
        char* r = p + off;
        off += (bytes + 255) & ~(size_t)255;
        return r;
    };
    const size_t nodeBf16 = (size_t)(N_NODES + 1) * DIM * sizeof(bf16_t); // +zero row
    bf16_t* gA       = (bf16_t*)carve(nodeBf16);
    bf16_t* gB       = (bf16_t*)carve(nodeBf16);
    int4*   nodeinfo = (int4*)carve((size_t)N_NODES * sizeof(int4));       // 2.4 MB
    int*    pos      = (int*)carve((size_t)nblk * (NB + 1) * sizeof(int)); // 1.15 MB
    int*    binned   = (int*)carve((size_t)nblk * STRIP * sizeof(int));    // 8 MB
    int*    packed   = (int*)carve((size_t)NB * CAP * sizeof(int));        // 19.2 MB
    (void)ws_size;

    // 1) Strip sort.
    lgcn_bin<<<nblk, 256, 0, stream>>>(row, col, pos, binned, EH);
    // 2) Per-bucket CSR + fused g0 init + zero rows.
    lgcn_build_csr<<<NB, 256, 0, stream>>>(pos, binned, nodeinfo, packed,
                                           ue, ie, gA, gB, nblk);
    // 3) Two full pulls (1 node/wave, lane=dim), then batch-only epilogue.
    const int pullGrid = (N_NODES + 3) / 4;        // 37500
    lgcn_pull<<<pullGrid, 256, 0, stream>>>(gA, nodeinfo, packed, gB);  // g1 = gB
    lgcn_pull<<<pullGrid, 256, 0, stream>>>(gB, nodeinfo, packed, gA);  // g2 = gA
    lgcn_final<<<(2 * BATCH + 3) / 4, 256, 0, stream>>>(
        ue, ie, gB, gA, nodeinfo, packed, uid, iid, out);
}